// Round 11
// baseline (413.294 us; speedup 1.0000x reference)
//
#include <hip/hip_runtime.h>
#include <cstdint>

#define DEV static __device__ __forceinline__

typedef __attribute__((ext_vector_type(8))) short bf16x8;
typedef __attribute__((ext_vector_type(4))) short bf16x4;
typedef __attribute__((ext_vector_type(4))) float f32x4;

// ---------------- problem constants ----------------
constexpr int BATCH = 2;
constexpr int G0 = 80;
constexpr int D1 = 78, D2 = 76, D3 = 74;
constexpr int C = 32;
constexpr int SD = 64, NSLOT = 8;
constexpr int D1S = D1 * D1 * D1;      // 474552
constexpr int D2S = D2 * D2 * D2;      // 438976
constexpr int D3S = D3 * D3 * D3;      // 405224
constexpr int NPOS1 = BATCH * D1S;
constexpr int NCHUNK4 = (D3S + 1023) / 1024;   // 396 blocks of 4x256 j
constexpr int NRED = 32;
constexpr int REDS = 544;                   // 512 upd + 16 rowsum + pad

// ---------------- workspace layout (bytes) ----------------
constexpr size_t A1_BYTES = (size_t)NPOS1 * C * 2;           // 60.7 MB
constexpr size_t A2_BYTES = (size_t)BATCH * D2S * C * 2;     // 56.2 MB
constexpr size_t S_OFF    = A1_BYTES + A2_BYTES;             // ~117 MB

DEV unsigned short f2bf(float f) {
  unsigned int u = __float_as_uint(f);
  u += 0x7fffu + ((u >> 16) & 1u);
  return (unsigned short)(u >> 16);
}
DEV unsigned int pk2(float a, float b) {
  return (unsigned int)f2bf(a) | ((unsigned int)f2bf(b) << 16);
}
DEV float bflo(unsigned int u) { return __uint_as_float(u << 16); }
DEV float bfhi(unsigned int u) { return __uint_as_float(u & 0xffff0000u); }
DEV float bfu(unsigned short h) { return __uint_as_float(((unsigned int)h) << 16); }

// async 16B global->LDS (DMA path, no VGPR round trip)
DEV void gload16(const void* g, void* l) {
  __builtin_amdgcn_global_load_lds(
      (const __attribute__((address_space(1))) void*)g,
      (__attribute__((address_space(3))) void*)l, 16, 0, 0);
}

// ---------------- weight prep + parallel red zeroing ----------------
__global__ __launch_bounds__(256) void k_wtr(const float* __restrict__ w1,
                                             const float* __restrict__ w2,
                                             const float* __restrict__ w3,
                                             unsigned short* __restrict__ wB1,
                                             unsigned short* __restrict__ wB2,
                                             unsigned short* __restrict__ wB3,
                                             float* __restrict__ red) {
  int idx = blockIdx.x * 256 + threadIdx.x;
  if (idx < 3 * NRED * REDS) red[idx] = 0.f;   // 52224 < 232*256
  if (idx < 4096) {
    int co = idx >> 7, k = idx & 127;
    int tap = k >> 2, ci = k & 3;
    wB1[idx] = (tap < 27) ? f2bf(w1[co * 108 + ci * 27 + tap]) : (unsigned short)0;
  }
  int i2 = idx - 4096;
  if (i2 >= 0 && i2 < 27648) {
    int ci = i2 & 31, co = (i2 >> 5) & 31, tap = i2 >> 10;
    wB2[i2] = f2bf(w2[(co * 32 + ci) * 27 + tap]);
  }
  int i3 = idx - 4096 - 27648;
  if (i3 >= 0 && i3 < 27648) {
    int ci = i3 & 31, co = (i3 >> 5) & 31, tap = i3 >> 10;
    wB3[i3] = f2bf(w3[(co * 32 + ci) * 27 + tap]);
  }
}

// ---------------- conv1 via MFMA — widened 16x4x8 tile, 512 threads ----------------
constexpr int C1NX = 5, C1NY = 20, C1NZ = 10;
__global__ __launch_bounds__(512, 4) void k_conv1m(const float* __restrict__ in,
                                                   const unsigned short* __restrict__ wB1,
                                                   const float* __restrict__ bias,
                                                   unsigned short* __restrict__ out) {
  __shared__ char smemc[69632];
  unsigned short* raw = (unsigned short*)smemc;
  int bid = blockIdx.x;
  int b = bid / (C1NX * C1NY * C1NZ);
  int t = bid % (C1NX * C1NY * C1NZ);
  int tx = t % C1NX;
  int ty = (t / C1NX) % C1NY;
  int tz = t / (C1NX * C1NY);
  int x0 = tx * 16, y0 = ty * 4, z0 = tz * 8;
  int tid = threadIdx.x;

  const float* ib = in + (size_t)b * 4 * (G0 * G0 * G0);
  for (int p = tid; p < 1080; p += 512) {
    int xl = p % 18, yl = (p / 18) % 6, zl = p / 108;
    int xg = min(x0 + xl, G0 - 1);
    int yg = min(y0 + yl, G0 - 1);
    int zg = min(z0 + zl, G0 - 1);
    size_t base = ((size_t)zg * G0 + yg) * G0 + xg;
    float v0 = ib[base];
    float v1 = ib[base + 512000];
    float v2 = ib[base + 2 * 512000];
    float v3 = ib[base + 3 * 512000];
    uint2 pk = {pk2(v0, v1), pk2(v2, v3)};
    *(uint2*)(raw + p * 4) = pk;
  }
  __syncthreads();

  int wv = tid >> 6, ln = tid & 63, q = ln >> 4, mr = ln & 15;

  bf16x8 Bf[4][2];
#pragma unroll
  for (int s = 0; s < 4; s++)
#pragma unroll
    for (int nt = 0; nt < 2; nt++)
      Bf[s][nt] = *(const bf16x8*)(wB1 + (nt * 16 + mr) * 128 + s * 32 + q * 8);

  f32x4 acc[4][2];
#pragma unroll
  for (int mi = 0; mi < 4; mi++)
#pragma unroll
    for (int nt = 0; nt < 2; nt++) acc[mi][nt] = (f32x4){0.f, 0.f, 0.f, 0.f};

  auto loadA = [&](int s, int mi) -> bf16x8 {
    int tA = min(s * 8 + q * 2, 26);
    int tB = min(s * 8 + q * 2 + 1, 26);
    int oA = (tA / 9) * 108 + ((tA / 3) % 3) * 18 + (tA % 3);
    int oB = (tB / 9) * 108 + ((tB / 3) % 3) * 18 + (tB % 3);
    int pbase = wv * 108 + mi * 18 + mr;
    bf16x8 af;
    *(bf16x4*)&af = *(const bf16x4*)(raw + (pbase + oA) * 4);
    *((bf16x4*)&af + 1) = *(const bf16x4*)(raw + (pbase + oB) * 4);
    return af;
  };

  bf16x8 A[4], nA[4];
#pragma unroll
  for (int mi = 0; mi < 4; mi++) A[mi] = loadA(0, mi);
#pragma unroll
  for (int s = 0; s < 4; s++) {
    if (s < 3) {
#pragma unroll
      for (int mi = 0; mi < 4; mi++) nA[mi] = loadA(s + 1, mi);
    }
#pragma unroll
    for (int mi = 0; mi < 4; mi++) {
      acc[mi][0] = __builtin_amdgcn_mfma_f32_16x16x32_bf16(A[mi], Bf[s][0], acc[mi][0], 0, 0, 0);
      acc[mi][1] = __builtin_amdgcn_mfma_f32_16x16x32_bf16(A[mi], Bf[s][1], acc[mi][1], 0, 0, 0);
    }
    if (s < 3) {
#pragma unroll
      for (int mi = 0; mi < 4; mi++) A[mi] = nA[mi];
    }
  }

  __syncthreads();
  float* sout = (float*)smemc;
#pragma unroll
  for (int mi = 0; mi < 4; mi++) {
    int mtile = wv * 4 + mi;
#pragma unroll
    for (int nt = 0; nt < 2; nt++) {
#pragma unroll
      for (int r = 0; r < 4; r++) {
        int pl = mtile * 16 + q * 4 + r;
        sout[pl * 34 + nt * 16 + mr] = acc[mi][nt][r];
      }
    }
  }
  __syncthreads();

  int xl = tid & 15, yl = (tid >> 4) & 3, zl = tid >> 6;
  int xg = x0 + xl, yg = y0 + yl, zg = z0 + zl;
  if (xg < D1 && yg < D1 && zg < D1) {
    float v[C];
#pragma unroll
    for (int c = 0; c < C; c++) v[c] = fmaxf(sout[tid * 34 + c] + bias[c], 0.f);
    unsigned short* op = out + ((size_t)b * D1S + (size_t)zg * (D1 * D1) + (size_t)yg * D1 + xg) * C;
#pragma unroll
    for (int g = 0; g < 4; g++) {
      uint4 o;
      o.x = pk2(v[g * 8 + 0], v[g * 8 + 1]);
      o.y = pk2(v[g * 8 + 2], v[g * 8 + 3]);
      o.z = pk2(v[g * 8 + 4], v[g * 8 + 5]);
      o.w = pk2(v[g * 8 + 6], v[g * 8 + 7]);
      ((uint4*)op)[g] = o;
    }
  }
}

// ---------------- MFMA implicit-GEMM conv (32->32) — R6 structure + 2-deep B prefetch ----------------
template <int DIN, int DOUT, bool DO_LN>
__global__ __launch_bounds__(512, 4) void k_convm(const unsigned short* __restrict__ actin,
                                                  const unsigned short* __restrict__ wB,
                                                  const float* __restrict__ bias,
                                                  const float* __restrict__ lng,
                                                  const float* __restrict__ lnb,
                                                  unsigned short* __restrict__ actout) {
  constexpr int DIN2 = DIN * DIN;
  constexpr size_t DINS = (size_t)DIN * DIN2;
  constexpr int DOUT2 = DOUT * DOUT;
  constexpr size_t DOUTS = (size_t)DOUT * DOUT2;
  constexpr int NX = (DOUT + 15) / 16, NY = (DOUT + 3) / 4, NZ = (DOUT + 7) / 8;
  constexpr int NROW = 1080;   // 18*6*10 halo rows

  __shared__ alignas(16) char smem[69632];
  unsigned short* s_halo = (unsigned short*)smem;

  int bid = blockIdx.x;
  int b = bid / (NX * NY * NZ);
  int t = bid % (NX * NY * NZ);
  int tx = t % NX;
  int t2 = t / NX;
  int ty = t2 % NY;
  int tz = t2 / NY;
  int x0 = tx * 16, y0 = ty * 4, z0 = tz * 8;
  const unsigned short* ib = actin + (size_t)b * DINS * 32;

  int tid = threadIdx.x;
  for (int ck = tid; ck < NROW * 4; ck += 512) {
    int pos = ck >> 2, slot = ck & 3;
    int sub = slot ^ ((pos >> 1) & 3);
    int xl = pos % 18;
    int p2 = pos / 18;
    int yl = p2 % 6;
    int zl = p2 / 6;
    int xg = min(x0 + xl, DIN - 1);
    int yg = min(y0 + yl, DIN - 1);
    int zg = min(z0 + zl, DIN - 1);
    gload16(ib + ((size_t)zg * DIN2 + (size_t)yg * DIN + xg) * 32 + sub * 8,
            (char*)s_halo + ck * 16);
  }

  int wv = tid >> 6, ln = tid & 63, q = ln >> 4, mr = ln & 15;

  f32x4 acc[4][2];
#pragma unroll
  for (int mi = 0; mi < 4; mi++)
#pragma unroll
    for (int nt = 0; nt < 2; nt++) acc[mi][nt] = (f32x4){0.f, 0.f, 0.f, 0.f};

  __syncthreads();

  const unsigned short* raw = s_halo;
  auto AF = [&](int pos) -> bf16x8 {
    return *(const bf16x8*)(raw + pos * 32 + ((q ^ ((pos >> 1) & 3)) << 3));
  };
  auto BW = [&](int tap, int half) -> bf16x8 {
    return *(const bf16x8*)(wB + tap * 1024 + (half * 16 + mr) * 32 + q * 8);
  };

  bf16x8 B0a = BW(0, 0), B1a = BW(0, 1);
  bf16x8 B0b = BW(1, 0), B1b = BW(1, 1);

  bf16x8 A[4], nA[4];
#pragma unroll
  for (int mi = 0; mi < 4; mi++) A[mi] = AF(wv * 108 + mi * 18 + mr);

#pragma unroll
  for (int tap = 0; tap < 27; tap++) {
    bf16x8 nB0, nB1;
    if (tap < 25) {
      nB0 = BW(tap + 2, 0);
      nB1 = BW(tap + 2, 1);
    }
    if (tap < 26) {
      int tn = tap + 1;
      int dz = tn / 9, dy = (tn / 3) % 3, dx = tn % 3;
      int base = (wv + dz) * 108 + dy * 18 + (mr + dx);
#pragma unroll
      for (int mi = 0; mi < 4; mi++) nA[mi] = AF(base + mi * 18);
    }
#pragma unroll
    for (int mi = 0; mi < 4; mi++) {
      acc[mi][0] = __builtin_amdgcn_mfma_f32_16x16x32_bf16(A[mi], B0a, acc[mi][0], 0, 0, 0);
      acc[mi][1] = __builtin_amdgcn_mfma_f32_16x16x32_bf16(A[mi], B1a, acc[mi][1], 0, 0, 0);
    }
    if (tap < 26) {
      B0a = B0b; B1a = B1b;
      if (tap < 25) { B0b = nB0; B1b = nB1; }
#pragma unroll
      for (int mi = 0; mi < 4; mi++) A[mi] = nA[mi];
    }
  }

  __syncthreads();
  float* s_out = (float*)smem;
#pragma unroll
  for (int mi = 0; mi < 4; mi++) {
    int mtile = wv * 4 + mi;
#pragma unroll
    for (int nt = 0; nt < 2; nt++) {
#pragma unroll
      for (int r = 0; r < 4; r++) {
        int pl = mtile * 16 + q * 4 + r;
        s_out[pl * 34 + nt * 16 + mr] = acc[mi][nt][r];
      }
    }
  }
  __syncthreads();

  int xl = tid & 15, yl = (tid >> 4) & 3, zl = tid >> 6;
  int xg = x0 + xl, yg = y0 + yl, zg = z0 + zl;
  bool valid = (xg < DOUT) && (yg < DOUT) && (zg < DOUT);
  float v[C];
  float s = 0.f, s2 = 0.f;
#pragma unroll
  for (int c = 0; c < C; c++) {
    float x = fmaxf(s_out[tid * 34 + c] + bias[c], 0.f);
    v[c] = x;
    s += x; s2 += x * x;
  }
  if (DO_LN) {
    float m = s * (1.f / C);
    float inv = rsqrtf(s2 * (1.f / C) - m * m + 1e-5f);
#pragma unroll
    for (int c = 0; c < C; c++) v[c] = (v[c] - m) * inv * lng[c] + lnb[c];
  }
  if (valid) {
    unsigned short* op = actout + ((size_t)b * DOUTS + (size_t)zg * DOUT2 + (size_t)yg * DOUT + xg) * 32;
#pragma unroll
    for (int g = 0; g < 4; g++) {
      uint4 o;
      o.x = pk2(v[g * 8 + 0], v[g * 8 + 1]);
      o.y = pk2(v[g * 8 + 2], v[g * 8 + 3]);
      o.z = pk2(v[g * 8 + 4], v[g * 8 + 5]);
      o.w = pk2(v[g * 8 + 6], v[g * 8 + 7]);
      ((uint4*)op)[g] = o;
    }
  }
}

// ---------------- initial qprep: qkB bf16 [b][16][32] (red zeroed in k_wtr) ----------------
__global__ __launch_bounds__(256) void k_qprep(const float* __restrict__ slots_src,
                                               const float* __restrict__ qlng,
                                               const float* __restrict__ qlnb,
                                               const float* __restrict__ qw,
                                               const float* __restrict__ kw,
                                               unsigned short* __restrict__ qkB) {
  __shared__ float ln_s[16][SD];
  __shared__ float q_s[16][SD];
  __shared__ float mv[16][2];
  int tid = threadIdx.x;
  if (tid < 16) {
    float s = 0.f, s2 = 0.f;
    for (int c = 0; c < SD; c++) { float v = slots_src[tid * SD + c]; s += v; s2 += v * v; }
    float m = s * (1.f / SD);
    mv[tid][0] = m;
    mv[tid][1] = rsqrtf(s2 * (1.f / SD) - m * m + 1e-5f);
  }
  __syncthreads();
  for (int idx = tid; idx < 16 * SD; idx += 256) {
    int r = idx >> 6, c = idx & 63;
    ln_s[r][c] = (slots_src[idx] - mv[r][0]) * mv[r][1] * qlng[c] + qlnb[c];
  }
  __syncthreads();
  for (int o = tid; o < 16 * SD; o += 256) {
    int r = o >> 6, d = o & 63;
    float s = 0.f;
    for (int c = 0; c < SD; c++) s = fmaf(ln_s[r][c], qw[d * SD + c], s);
    q_s[r][d] = s;
  }
  __syncthreads();
  for (int o = tid; o < 1024; o += 256) {
    int b = o >> 9, i = (o >> 5) & 15, c = o & 31;
    unsigned short v = 0;
    if (i < 8) {
      float s = 0.f;
      for (int d = 0; d < SD; d++) s = fmaf(q_s[(b * 8 + i)][d], kw[d * C + c], s);
      v = f2bf(s);
    }
    qkB[o] = v;
  }
}

// ---------------- attention: 4 j-chunks per block, wave-private pipeline, one combine ----------------
// Wave wv touches ONLY f_s/dots_s/a_s rows [wv*64, wv*64+64) in phases 0-2,
// so the chunk loop needs only per-wave lgkmcnt fences (incl. the loop-end
// fence for the WAR hazard: next chunk's f_s writes vs this chunk's reads).
// uacc/racc accumulate across chunks; ONE combine + atomic flush per block.
__global__ __launch_bounds__(256) void k_attn(const unsigned short* __restrict__ feat,
                                              const unsigned short* __restrict__ qkB,
                                              float* __restrict__ red,
                                              float* __restrict__ attn_out,
                                              int last) {
  __shared__ alignas(16) char smem[36992];
  char* f_s = smem;
  float* dots_s = (float*)(smem + 20480);
  unsigned short* a_s = (unsigned short*)(smem + 32768);

  int tid = threadIdx.x;
  int b = blockIdx.y;
  int wv = tid >> 6, ln = tid & 63, q = ln >> 4, mr = ln & 15;
  int sw = (tid >> 3) & 3;

  bf16x8 Aq = *(const bf16x8*)(qkB + b * 512 + mr * 32 + q * 8);

  f32x4 uacc0 = (f32x4){0.f, 0.f, 0.f, 0.f};
  f32x4 uacc1 = (f32x4){0.f, 0.f, 0.f, 0.f};
  f32x4 racc  = (f32x4){0.f, 0.f, 0.f, 0.f};

#pragma unroll 1
  for (int cc = 0; cc < 4; cc++) {
    int j0 = (blockIdx.x * 4 + cc) * 256;
    int j = j0 + tid;
    bool valid = j < D3S;

    // phase 0: global feat -> wave-private LDS rows (granule-swizzled) + ones
    uint4 f4[4];
    if (valid) {
      const uint4* fp = (const uint4*)(feat + ((size_t)b * D3S + j) * C);
#pragma unroll
      for (int g = 0; g < 4; g++) f4[g] = fp[g];
    } else {
#pragma unroll
      for (int g = 0; g < 4; g++) f4[g] = (uint4){0u, 0u, 0u, 0u};
    }
#pragma unroll
    for (int g = 0; g < 4; g++) *(uint4*)(f_s + tid * 80 + ((g ^ sw) << 4)) = f4[g];
    *(uint4*)(f_s + tid * 80 + 64) = (uint4){0x3f80u, 0u, 0u, 0u};
    asm volatile("s_waitcnt lgkmcnt(0)" ::: "memory");
    __builtin_amdgcn_sched_barrier(0);

    // phase 1: dots via MFMA (wave-private rows)
    f32x4 dacc[4];
#pragma unroll
    for (int mt = 0; mt < 4; mt++) {
      int jrow = wv * 64 + mt * 16 + mr;
      int sw1 = (jrow >> 3) & 3;
      bf16x8 Bf = *(const bf16x8*)(f_s + jrow * 80 + ((q ^ sw1) << 4));
      dacc[mt] = __builtin_amdgcn_mfma_f32_16x16x32_bf16(
          Aq, Bf, (f32x4){0.f, 0.f, 0.f, 0.f}, 0, 0, 0);
    }
    if (q < 2) {
#pragma unroll
      for (int mt = 0; mt < 4; mt++)
#pragma unroll
        for (int r = 0; r < 4; r++)
          dots_s[(wv * 64 + mt * 16 + mr) * 12 + q * 4 + r] = dacc[mt][r];
    }
    asm volatile("s_waitcnt lgkmcnt(0)" ::: "memory");
    __builtin_amdgcn_sched_barrier(0);

    // softmax over slots (thread = its j)
    float attn[NSLOT];
    {
      uint4 d0 = *(const uint4*)(dots_s + tid * 12);
      uint4 d1 = *(const uint4*)(dots_s + tid * 12 + 4);
      float dot[NSLOT] = {__uint_as_float(d0.x), __uint_as_float(d0.y),
                          __uint_as_float(d0.z), __uint_as_float(d0.w),
                          __uint_as_float(d1.x), __uint_as_float(d1.y),
                          __uint_as_float(d1.z), __uint_as_float(d1.w)};
      float mx = -1e30f;
#pragma unroll
      for (int i = 0; i < NSLOT; i++) { dot[i] *= 0.125f; mx = fmaxf(mx, dot[i]); }
      float ssum = 0.f;
#pragma unroll
      for (int i = 0; i < NSLOT; i++) { float e = __expf(dot[i] - mx); attn[i] = e; ssum += e; }
      float invs = 1.f / ssum;
#pragma unroll
      for (int i = 0; i < NSLOT; i++)
        attn[i] = valid ? fmaf(attn[i], invs, 1e-8f) : 0.f;
    }
#pragma unroll
    for (int i = 0; i < NSLOT; i++)
      a_s[i * 264 + tid] = f2bf(attn[i]);
    if (last && valid) {
#pragma unroll
      for (int i = 0; i < NSLOT; i++)
        attn_out[(size_t)(b * NSLOT + i) * D3S + j] = attn[i];
    }
    asm volatile("s_waitcnt lgkmcnt(0)" ::: "memory");
    __builtin_amdgcn_sched_barrier(0);

    // phase 2: per-wave K-split MFMA; accumulate across chunks
    {
      int kb0 = wv * 64;
#pragma unroll
      for (int ks = 0; ks < 2; ks++) {
        int kb = kb0 + ks * 32;
        bf16x8 Aa = *(const bf16x8*)(a_s + (mr & 7) * 264 + kb + q * 8);
        int jb = kb + q * 8;
        int sw2 = (jb >> 3) & 3;
        const char* colp = f_s + jb * 80;
        bf16x8 Bf0, Bf1, Bo;
        short* p0 = (short*)&Bf0;
        short* p1 = (short*)&Bf1;
        short* po = (short*)&Bo;
#pragma unroll
        for (int e = 0; e < 8; e++) {
          const char* rowp = colp + e * 80;
          p0[e] = *(const short*)(rowp + ((((mr >> 3) ^ sw2) << 4)) + (mr & 7) * 2);
          p1[e] = *(const short*)(rowp + ((((2 + (mr >> 3)) ^ sw2) << 4)) + (mr & 7) * 2);
          po[e] = *(const short*)(rowp + 64 + mr * 2);
        }
        uacc0 = __builtin_amdgcn_mfma_f32_16x16x32_bf16(Aa, Bf0, uacc0, 0, 0, 0);
        uacc1 = __builtin_amdgcn_mfma_f32_16x16x32_bf16(Aa, Bf1, uacc1, 0, 0, 0);
        racc  = __builtin_amdgcn_mfma_f32_16x16x32_bf16(Aa, Bo,  racc,  0, 0, 0);
      }
    }
    // WAR fence: next chunk's f_s/a_s writes must not pass this chunk's reads
    asm volatile("s_waitcnt lgkmcnt(0)" ::: "memory");
    __builtin_amdgcn_sched_barrier(0);
  }

  // block-level combine (overlay on f_s; barrier covers all waves' last reads)
  float* part = (float*)smem;               // 4 waves x 264 floats
  __syncthreads();
  if (q < 2) {
    int base = wv * 264;
#pragma unroll
    for (int r = 0; r < 4; r++) {
      int i = q * 4 + r;
      part[base + i * 32 + mr] = uacc0[r];
      part[base + i * 32 + 16 + mr] = uacc1[r];
    }
    if (mr == 0) {
#pragma unroll
      for (int r = 0; r < 4; r++) part[base + 256 + q * 4 + r] = racc[r];
    }
  }
  __syncthreads();
  int gsl = blockIdx.x & (NRED - 1);
  if (tid < 256) {
    float s = part[tid] + part[264 + tid] + part[528 + tid] + part[792 + tid];
    atomicAdd(&red[gsl * REDS + b * 256 + tid], s);
  }
  if (tid < 8) {
    float s = part[256 + tid] + part[264 + 256 + tid] +
              part[528 + 256 + tid] + part[792 + 256 + tid];
    atomicAdd(&red[gsl * REDS + 512 + b * 8 + tid], s);
  }
}

// ---------------- final: 16 blocks (one per slot-row); NO red zeroing (triple-buffered) ----------------
__global__ __launch_bounds__(256) void k_final(const float* __restrict__ slots_src,
                                               const float* __restrict__ red,
                                               const float* __restrict__ vw,
                                               const float* __restrict__ wih,
                                               const float* __restrict__ whh,
                                               const float* __restrict__ bih,
                                               const float* __restrict__ bhh,
                                               const float* __restrict__ rlng,
                                               const float* __restrict__ rlnb,
                                               const float* __restrict__ w1,
                                               const float* __restrict__ rb1,
                                               const float* __restrict__ w2,
                                               const float* __restrict__ rb2,
                                               const float* __restrict__ qlng,
                                               const float* __restrict__ qlnb,
                                               const float* __restrict__ qw,
                                               const float* __restrict__ kw,
                                               unsigned short* __restrict__ qkB,
                                               float* __restrict__ slots_dst,
                                               float* __restrict__ out_slots,
                                               int last) {
  __shared__ float updc[32];
  __shared__ float rs_s;
  __shared__ float hh[64], upd_s[64], gg[384], hn[64], tl[64], m1[128], qv[64], ov_s[64];
  int tid = threadIdx.x;
  int r = blockIdx.x;            // 0..15
  int b = r >> 3, islot = r & 7;

  if (tid < 32) {
    float s = 0.f;
#pragma unroll
    for (int g = 0; g < NRED; g++) s += red[g * REDS + r * 32 + tid];
    updc[tid] = s;
  } else if (tid == 32) {
    float s = 0.f;
#pragma unroll
    for (int g = 0; g < NRED; g++) s += red[g * REDS + 512 + r];
    rs_s = s;
  }
  if (tid >= 64 && tid < 128) hh[tid - 64] = slots_src[r * 64 + (tid - 64)];
  __syncthreads();
  if (tid < 64) {
    float s = 0.f;
    for (int c = 0; c < 32; c++) s = fmaf(updc[c], vw[tid * 32 + c], s);
    upd_s[tid] = s / rs_s;
  }
  __syncthreads();
  for (int o = tid; o < 384; o += 256) {
    int sel = o >= 192;
    int cg = o - sel * 192;
    const float* sp = sel ? hh : upd_s;
    const float* w  = sel ? whh : wih;
    float s = sel ? bhh[cg] : bih[cg];
    for (int d = 0; d < 64; d++) s = fmaf(sp[d], w[cg * 64 + d], s);
    gg[o] = s;
  }
  __syncthreads();
  if (tid < 64) {
    float rg = 1.f / (1.f + __expf(-(gg[tid] + gg[192 + tid])));
    float zg = 1.f / (1.f + __expf(-(gg[64 + tid] + gg[256 + tid])));
    float ng = tanhf(gg[128 + tid] + rg * gg[320 + tid]);
    hn[tid] = (1.f - zg) * ng + zg * hh[tid];
  }
  __syncthreads();
  if (tid < 64) {
    float v = hn[tid];
    float s = v, s2 = v * v;
#pragma unroll
    for (int m = 1; m < 64; m <<= 1) { s += __shfl_xor(s, m); s2 += __shfl_xor(s2, m); }
    float mean = s * (1.f / 64);
    float inv = rsqrtf(s2 * (1.f / 64) - mean * mean + 1e-5f);
    tl[tid] = (v - mean) * inv * rlng[tid] + rlnb[tid];
  }
  __syncthreads();
  if (tid < 128) {
    float s = rb1[tid];
    for (int d = 0; d < 64; d++) s = fmaf(tl[d], w1[tid * 64 + d], s);
    m1[tid] = fmaxf(s, 0.f);
  }
  __syncthreads();
  if (tid < 64) {
    float s = rb2[tid];
    for (int j = 0; j < 128; j++) s = fmaf(m1[j], w2[tid * 128 + j], s);
    float ov = hn[tid] + s;
    slots_dst[r * 64 + tid] = ov;
    ov_s[tid] = ov;
    if (last) out_slots[r * 64 + tid] = ov;
  }
  __syncthreads();
  if (tid < 64) {
    float v = ov_s[tid];
    float s = v, s2 = v * v;
#pragma unroll
    for (int m = 1; m < 64; m <<= 1) { s += __shfl_xor(s, m); s2 += __shfl_xor(s2, m); }
    float mean = s * (1.f / 64);
    float inv = rsqrtf(s2 * (1.f / 64) - mean * mean + 1e-5f);
    tl[tid] = (v - mean) * inv * qlng[tid] + qlnb[tid];
  }
  __syncthreads();
  if (tid < 64) {
    float s = 0.f;
    for (int c = 0; c < 64; c++) s = fmaf(tl[c], qw[tid * 64 + c], s);
    qv[tid] = s;
  }
  __syncthreads();
  if (tid < 32) {
    float s = 0.f;
    for (int d = 0; d < 64; d++) s = fmaf(qv[d], kw[d * 32 + tid], s);
    qkB[b * 512 + islot * 32 + tid] = f2bf(s);
  }
}

// ---------------- host launch ----------------
extern "C" void kernel_launch(void* const* d_in, const int* in_sizes, int n_in,
                              void* d_out, int out_size, void* d_ws, size_t ws_size,
                              hipStream_t stream) {
  const float* slots = (const float*)d_in[0];
  const float* oin   = (const float*)d_in[1];
  const float* w1    = (const float*)d_in[2];
  const float* b1    = (const float*)d_in[3];
  const float* w2    = (const float*)d_in[4];
  const float* b2    = (const float*)d_in[5];
  const float* w3    = (const float*)d_in[6];
  const float* b3    = (const float*)d_in[7];
  const float* kw    = (const float*)d_in[8];
  const float* vw    = (const float*)d_in[9];
  const float* qlng  = (const float*)d_in[10];
  const float* qlnb  = (const float*)d_in[11];
  const float* qw    = (const float*)d_in[12];
  const float* wih   = (const float*)d_in[13];
  const float* whh   = (const float*)d_in[14];
  const float* bih   = (const float*)d_in[15];
  const float* bhh   = (const float*)d_in[16];
  const float* rlng  = (const float*)d_in[17];
  const float* rlnb  = (const float*)d_in[18];
  const float* rw1   = (const float*)d_in[19];
  const float* rb1   = (const float*)d_in[20];
  const float* rw2   = (const float*)d_in[21];
  const float* rb2   = (const float*)d_in[22];
  const float* flng  = (const float*)d_in[23];
  const float* flnb  = (const float*)d_in[24];

  char* ws = (char*)d_ws;
  unsigned short* act1 = (unsigned short*)ws;
  unsigned short* act2 = (unsigned short*)(ws + A1_BYTES);
  unsigned short* feat = act1;
  unsigned short* wB1 = (unsigned short*)(ws + S_OFF);
  unsigned short* wB2 = wB1 + 4096;
  unsigned short* wB3 = wB2 + 27648;
  unsigned short* qkB = wB3 + 27648;           // [2][16][32] bf16
  float* red  = (float*)(qkB + 1024);          // 3 * NRED*REDS floats
  float* sl0  = red + 3 * NRED * REDS;
  float* sl1  = sl0 + 1024;

  float* out_slots = (float*)d_out;
  float* attn_out  = (float*)d_out + 1024;

  k_wtr<<<232, 256, 0, stream>>>(w1, w2, w3, wB1, wB2, wB3, red);
  k_conv1m<<<C1NX * C1NY * C1NZ * BATCH, 512, 0, stream>>>(oin, wB1, b1, act1);
  {
    constexpr int NB2 = ((D2 + 15) / 16) * ((D2 + 3) / 4) * ((D2 + 7) / 8) * BATCH;
    k_convm<D1, D2, false><<<NB2, 512, 0, stream>>>(act1, wB2, b2, nullptr, nullptr, act2);
  }
  {
    constexpr int NB3 = ((D3 + 15) / 16) * ((D3 + 3) / 4) * ((D3 + 7) / 8) * BATCH;
    k_convm<D2, D3, true><<<NB3, 512, 0, stream>>>(act2, wB3, b3, flng, flnb, feat);
  }

  k_qprep<<<1, 256, 0, stream>>>(slots, qlng, qlnb, qw, kw, qkB);
  const float* src = slots;
  float* dst = sl0;
  for (int it = 0; it < 3; it++) {
    int last = (it == 2);
    float* red_it = red + it * (NRED * REDS);
    k_attn<<<dim3(NCHUNK4, BATCH), 256, 0, stream>>>(feat, qkB, red_it, attn_out, last);
    k_final<<<16, 256, 0, stream>>>(src, red_it, vw, wih, whh, bih, bhh,
                                    rlng, rlnb, rw1, rb1, rw2, rb2,
                                    qlng, qlnb, qw, kw, qkB, dst, out_slots, last);
    src = dst;
    dst = (it == 0) ? sl1 : sl0;
  }
}

// Round 12
// 406.051 us; speedup vs baseline: 1.0178x; 1.0178x over previous
//
#include <hip/hip_runtime.h>
#include <cstdint>

#define DEV static __device__ __forceinline__

typedef __attribute__((ext_vector_type(8))) short bf16x8;
typedef __attribute__((ext_vector_type(4))) short bf16x4;
typedef __attribute__((ext_vector_type(4))) float f32x4;

// ---------------- problem constants ----------------
constexpr int BATCH = 2;
constexpr int G0 = 80;
constexpr int D1 = 78, D2 = 76, D3 = 74;
constexpr int C = 32;
constexpr int SD = 64, NSLOT = 8;
constexpr int D1S = D1 * D1 * D1;      // 474552
constexpr int D2S = D2 * D2 * D2;      // 438976
constexpr int D3S = D3 * D3 * D3;      // 405224
constexpr int NPOS1 = BATCH * D1S;
constexpr int NCHUNK4 = (D3S + 1023) / 1024;   // 396 blocks of 4x256 j
constexpr int NRED = 32;
constexpr int REDS = 544;                   // 512 upd + 16 rowsum + pad

// ---------------- workspace layout (bytes) ----------------
constexpr size_t A1_BYTES = (size_t)NPOS1 * C * 2;           // 60.7 MB
constexpr size_t A2_BYTES = (size_t)BATCH * D2S * C * 2;     // 56.2 MB
constexpr size_t S_OFF    = A1_BYTES + A2_BYTES;             // ~117 MB

DEV unsigned short f2bf(float f) {
  unsigned int u = __float_as_uint(f);
  u += 0x7fffu + ((u >> 16) & 1u);
  return (unsigned short)(u >> 16);
}
DEV unsigned int pk2(float a, float b) {
  return (unsigned int)f2bf(a) | ((unsigned int)f2bf(b) << 16);
}
DEV float bflo(unsigned int u) { return __uint_as_float(u << 16); }
DEV float bfhi(unsigned int u) { return __uint_as_float(u & 0xffff0000u); }
DEV float bfu(unsigned short h) { return __uint_as_float(((unsigned int)h) << 16); }

// async 16B global->LDS (DMA path, no VGPR round trip)
DEV void gload16(const void* g, void* l) {
  __builtin_amdgcn_global_load_lds(
      (const __attribute__((address_space(1))) void*)g,
      (__attribute__((address_space(3))) void*)l, 16, 0, 0);
}

// ---------------- weight prep + red zeroing + (block 232) qprep ----------------
__global__ __launch_bounds__(256) void k_wtr(const float* __restrict__ w1,
                                             const float* __restrict__ w2,
                                             const float* __restrict__ w3,
                                             unsigned short* __restrict__ wB1,
                                             unsigned short* __restrict__ wB2,
                                             unsigned short* __restrict__ wB3,
                                             float* __restrict__ red,
                                             const float* __restrict__ slots_src,
                                             const float* __restrict__ qlng,
                                             const float* __restrict__ qlnb,
                                             const float* __restrict__ qw,
                                             const float* __restrict__ kw,
                                             unsigned short* __restrict__ qkB) {
  int tid = threadIdx.x;
  if (blockIdx.x == 232) {
    // initial qprep (independent of weights)
    __shared__ float ln_s[16][SD];
    __shared__ float q_s[16][SD];
    __shared__ float mv[16][2];
    if (tid < 16) {
      float s = 0.f, s2 = 0.f;
      for (int c = 0; c < SD; c++) { float v = slots_src[tid * SD + c]; s += v; s2 += v * v; }
      float m = s * (1.f / SD);
      mv[tid][0] = m;
      mv[tid][1] = rsqrtf(s2 * (1.f / SD) - m * m + 1e-5f);
    }
    __syncthreads();
    for (int idx = tid; idx < 16 * SD; idx += 256) {
      int r = idx >> 6, c = idx & 63;
      ln_s[r][c] = (slots_src[idx] - mv[r][0]) * mv[r][1] * qlng[c] + qlnb[c];
    }
    __syncthreads();
    for (int o = tid; o < 16 * SD; o += 256) {
      int r = o >> 6, d = o & 63;
      float s = 0.f;
      for (int c = 0; c < SD; c++) s = fmaf(ln_s[r][c], qw[d * SD + c], s);
      q_s[r][d] = s;
    }
    __syncthreads();
    for (int o = tid; o < 1024; o += 256) {
      int b = o >> 9, i = (o >> 5) & 15, c = o & 31;
      unsigned short v = 0;
      if (i < 8) {
        float s = 0.f;
        for (int d = 0; d < SD; d++) s = fmaf(q_s[(b * 8 + i)][d], kw[d * C + c], s);
        v = f2bf(s);
      }
      qkB[o] = v;
    }
    return;
  }
  int idx = blockIdx.x * 256 + tid;
  if (idx < 3 * NRED * REDS) red[idx] = 0.f;   // 52224 < 232*256
  if (idx < 4096) {
    int co = idx >> 7, k = idx & 127;
    int tap = k >> 2, ci = k & 3;
    wB1[idx] = (tap < 27) ? f2bf(w1[co * 108 + ci * 27 + tap]) : (unsigned short)0;
  }
  int i2 = idx - 4096;
  if (i2 >= 0 && i2 < 27648) {
    int ci = i2 & 31, co = (i2 >> 5) & 31, tap = i2 >> 10;
    wB2[i2] = f2bf(w2[(co * 32 + ci) * 27 + tap]);
  }
  int i3 = idx - 4096 - 27648;
  if (i3 >= 0 && i3 < 27648) {
    int ci = i3 & 31, co = (i3 >> 5) & 31, tap = i3 >> 10;
    wB3[i3] = f2bf(w3[(co * 32 + ci) * 27 + tap]);
  }
}

// ---------------- conv1 via MFMA — widened 16x4x8 tile, 512 threads ----------------
constexpr int C1NX = 5, C1NY = 20, C1NZ = 10;
__global__ __launch_bounds__(512, 4) void k_conv1m(const float* __restrict__ in,
                                                   const unsigned short* __restrict__ wB1,
                                                   const float* __restrict__ bias,
                                                   unsigned short* __restrict__ out) {
  __shared__ char smemc[69632];
  unsigned short* raw = (unsigned short*)smemc;
  int bid = blockIdx.x;
  int b = bid / (C1NX * C1NY * C1NZ);
  int t = bid % (C1NX * C1NY * C1NZ);
  int tx = t % C1NX;
  int ty = (t / C1NX) % C1NY;
  int tz = t / (C1NX * C1NY);
  int x0 = tx * 16, y0 = ty * 4, z0 = tz * 8;
  int tid = threadIdx.x;

  const float* ib = in + (size_t)b * 4 * (G0 * G0 * G0);
  for (int p = tid; p < 1080; p += 512) {
    int xl = p % 18, yl = (p / 18) % 6, zl = p / 108;
    int xg = min(x0 + xl, G0 - 1);
    int yg = min(y0 + yl, G0 - 1);
    int zg = min(z0 + zl, G0 - 1);
    size_t base = ((size_t)zg * G0 + yg) * G0 + xg;
    float v0 = ib[base];
    float v1 = ib[base + 512000];
    float v2 = ib[base + 2 * 512000];
    float v3 = ib[base + 3 * 512000];
    uint2 pk = {pk2(v0, v1), pk2(v2, v3)};
    *(uint2*)(raw + p * 4) = pk;
  }
  __syncthreads();

  int wv = tid >> 6, ln = tid & 63, q = ln >> 4, mr = ln & 15;

  bf16x8 Bf[4][2];
#pragma unroll
  for (int s = 0; s < 4; s++)
#pragma unroll
    for (int nt = 0; nt < 2; nt++)
      Bf[s][nt] = *(const bf16x8*)(wB1 + (nt * 16 + mr) * 128 + s * 32 + q * 8);

  f32x4 acc[4][2];
#pragma unroll
  for (int mi = 0; mi < 4; mi++)
#pragma unroll
    for (int nt = 0; nt < 2; nt++) acc[mi][nt] = (f32x4){0.f, 0.f, 0.f, 0.f};

  auto loadA = [&](int s, int mi) -> bf16x8 {
    int tA = min(s * 8 + q * 2, 26);
    int tB = min(s * 8 + q * 2 + 1, 26);
    int oA = (tA / 9) * 108 + ((tA / 3) % 3) * 18 + (tA % 3);
    int oB = (tB / 9) * 108 + ((tB / 3) % 3) * 18 + (tB % 3);
    int pbase = wv * 108 + mi * 18 + mr;
    bf16x8 af;
    *(bf16x4*)&af = *(const bf16x4*)(raw + (pbase + oA) * 4);
    *((bf16x4*)&af + 1) = *(const bf16x4*)(raw + (pbase + oB) * 4);
    return af;
  };

  bf16x8 A[4], nA[4];
#pragma unroll
  for (int mi = 0; mi < 4; mi++) A[mi] = loadA(0, mi);
#pragma unroll
  for (int s = 0; s < 4; s++) {
    if (s < 3) {
#pragma unroll
      for (int mi = 0; mi < 4; mi++) nA[mi] = loadA(s + 1, mi);
    }
#pragma unroll
    for (int mi = 0; mi < 4; mi++) {
      acc[mi][0] = __builtin_amdgcn_mfma_f32_16x16x32_bf16(A[mi], Bf[s][0], acc[mi][0], 0, 0, 0);
      acc[mi][1] = __builtin_amdgcn_mfma_f32_16x16x32_bf16(A[mi], Bf[s][1], acc[mi][1], 0, 0, 0);
    }
    if (s < 3) {
#pragma unroll
      for (int mi = 0; mi < 4; mi++) A[mi] = nA[mi];
    }
  }

  __syncthreads();
  float* sout = (float*)smemc;
#pragma unroll
  for (int mi = 0; mi < 4; mi++) {
    int mtile = wv * 4 + mi;
#pragma unroll
    for (int nt = 0; nt < 2; nt++) {
#pragma unroll
      for (int r = 0; r < 4; r++) {
        int pl = mtile * 16 + q * 4 + r;
        sout[pl * 34 + nt * 16 + mr] = acc[mi][nt][r];
      }
    }
  }
  __syncthreads();

  int xl = tid & 15, yl = (tid >> 4) & 3, zl = tid >> 6;
  int xg = x0 + xl, yg = y0 + yl, zg = z0 + zl;
  if (xg < D1 && yg < D1 && zg < D1) {
    float v[C];
#pragma unroll
    for (int c = 0; c < C; c++) v[c] = fmaxf(sout[tid * 34 + c] + bias[c], 0.f);
    unsigned short* op = out + ((size_t)b * D1S + (size_t)zg * (D1 * D1) + (size_t)yg * D1 + xg) * C;
#pragma unroll
    for (int g = 0; g < 4; g++) {
      uint4 o;
      o.x = pk2(v[g * 8 + 0], v[g * 8 + 1]);
      o.y = pk2(v[g * 8 + 2], v[g * 8 + 3]);
      o.z = pk2(v[g * 8 + 4], v[g * 8 + 5]);
      o.w = pk2(v[g * 8 + 6], v[g * 8 + 7]);
      ((uint4*)op)[g] = o;
    }
  }
}

// ---------------- MFMA implicit-GEMM conv (32->32) — R6 structure + 2-deep B prefetch ----------------
template <int DIN, int DOUT, bool DO_LN>
__global__ __launch_bounds__(512, 4) void k_convm(const unsigned short* __restrict__ actin,
                                                  const unsigned short* __restrict__ wB,
                                                  const float* __restrict__ bias,
                                                  const float* __restrict__ lng,
                                                  const float* __restrict__ lnb,
                                                  unsigned short* __restrict__ actout) {
  constexpr int DIN2 = DIN * DIN;
  constexpr size_t DINS = (size_t)DIN * DIN2;
  constexpr int DOUT2 = DOUT * DOUT;
  constexpr size_t DOUTS = (size_t)DOUT * DOUT2;
  constexpr int NX = (DOUT + 15) / 16, NY = (DOUT + 3) / 4, NZ = (DOUT + 7) / 8;
  constexpr int NROW = 1080;   // 18*6*10 halo rows

  __shared__ alignas(16) char smem[69632];
  unsigned short* s_halo = (unsigned short*)smem;

  int bid = blockIdx.x;
  int b = bid / (NX * NY * NZ);
  int t = bid % (NX * NY * NZ);
  int tx = t % NX;
  int t2 = t / NX;
  int ty = t2 % NY;
  int tz = t2 / NY;
  int x0 = tx * 16, y0 = ty * 4, z0 = tz * 8;
  const unsigned short* ib = actin + (size_t)b * DINS * 32;

  int tid = threadIdx.x;
  for (int ck = tid; ck < NROW * 4; ck += 512) {
    int pos = ck >> 2, slot = ck & 3;
    int sub = slot ^ ((pos >> 1) & 3);
    int xl = pos % 18;
    int p2 = pos / 18;
    int yl = p2 % 6;
    int zl = p2 / 6;
    int xg = min(x0 + xl, DIN - 1);
    int yg = min(y0 + yl, DIN - 1);
    int zg = min(z0 + zl, DIN - 1);
    gload16(ib + ((size_t)zg * DIN2 + (size_t)yg * DIN + xg) * 32 + sub * 8,
            (char*)s_halo + ck * 16);
  }

  int wv = tid >> 6, ln = tid & 63, q = ln >> 4, mr = ln & 15;

  f32x4 acc[4][2];
#pragma unroll
  for (int mi = 0; mi < 4; mi++)
#pragma unroll
    for (int nt = 0; nt < 2; nt++) acc[mi][nt] = (f32x4){0.f, 0.f, 0.f, 0.f};

  __syncthreads();

  const unsigned short* raw = s_halo;
  auto AF = [&](int pos) -> bf16x8 {
    return *(const bf16x8*)(raw + pos * 32 + ((q ^ ((pos >> 1) & 3)) << 3));
  };
  auto BW = [&](int tap, int half) -> bf16x8 {
    return *(const bf16x8*)(wB + tap * 1024 + (half * 16 + mr) * 32 + q * 8);
  };

  bf16x8 B0a = BW(0, 0), B1a = BW(0, 1);
  bf16x8 B0b = BW(1, 0), B1b = BW(1, 1);

  bf16x8 A[4], nA[4];
#pragma unroll
  for (int mi = 0; mi < 4; mi++) A[mi] = AF(wv * 108 + mi * 18 + mr);

#pragma unroll
  for (int tap = 0; tap < 27; tap++) {
    bf16x8 nB0, nB1;
    if (tap < 25) {
      nB0 = BW(tap + 2, 0);
      nB1 = BW(tap + 2, 1);
    }
    if (tap < 26) {
      int tn = tap + 1;
      int dz = tn / 9, dy = (tn / 3) % 3, dx = tn % 3;
      int base = (wv + dz) * 108 + dy * 18 + (mr + dx);
#pragma unroll
      for (int mi = 0; mi < 4; mi++) nA[mi] = AF(base + mi * 18);
    }
#pragma unroll
    for (int mi = 0; mi < 4; mi++) {
      acc[mi][0] = __builtin_amdgcn_mfma_f32_16x16x32_bf16(A[mi], B0a, acc[mi][0], 0, 0, 0);
      acc[mi][1] = __builtin_amdgcn_mfma_f32_16x16x32_bf16(A[mi], B1a, acc[mi][1], 0, 0, 0);
    }
    if (tap < 26) {
      B0a = B0b; B1a = B1b;
      if (tap < 25) { B0b = nB0; B1b = nB1; }
#pragma unroll
      for (int mi = 0; mi < 4; mi++) A[mi] = nA[mi];
    }
  }

  __syncthreads();
  float* s_out = (float*)smem;
#pragma unroll
  for (int mi = 0; mi < 4; mi++) {
    int mtile = wv * 4 + mi;
#pragma unroll
    for (int nt = 0; nt < 2; nt++) {
#pragma unroll
      for (int r = 0; r < 4; r++) {
        int pl = mtile * 16 + q * 4 + r;
        s_out[pl * 34 + nt * 16 + mr] = acc[mi][nt][r];
      }
    }
  }
  __syncthreads();

  int xl = tid & 15, yl = (tid >> 4) & 3, zl = tid >> 6;
  int xg = x0 + xl, yg = y0 + yl, zg = z0 + zl;
  bool valid = (xg < DOUT) && (yg < DOUT) && (zg < DOUT);
  float v[C];
  float s = 0.f, s2 = 0.f;
#pragma unroll
  for (int c = 0; c < C; c++) {
    float x = fmaxf(s_out[tid * 34 + c] + bias[c], 0.f);
    v[c] = x;
    s += x; s2 += x * x;
  }
  if (DO_LN) {
    float m = s * (1.f / C);
    float inv = rsqrtf(s2 * (1.f / C) - m * m + 1e-5f);
#pragma unroll
    for (int c = 0; c < C; c++) v[c] = (v[c] - m) * inv * lng[c] + lnb[c];
  }
  if (valid) {
    unsigned short* op = actout + ((size_t)b * DOUTS + (size_t)zg * DOUT2 + (size_t)yg * DOUT + xg) * 32;
#pragma unroll
    for (int g = 0; g < 4; g++) {
      uint4 o;
      o.x = pk2(v[g * 8 + 0], v[g * 8 + 1]);
      o.y = pk2(v[g * 8 + 2], v[g * 8 + 3]);
      o.z = pk2(v[g * 8 + 4], v[g * 8 + 5]);
      o.w = pk2(v[g * 8 + 6], v[g * 8 + 7]);
      ((uint4*)op)[g] = o;
    }
  }
}

// ---------------- attention: 4 j-chunks/block, wave-private pipeline, const-Bo, one combine ----------------
__global__ __launch_bounds__(256) void k_attn(const unsigned short* __restrict__ feat,
                                              const unsigned short* __restrict__ qkB,
                                              float* __restrict__ red,
                                              float* __restrict__ attn_out,
                                              int last) {
  __shared__ alignas(16) char smem[36992];
  char* f_s = smem;
  float* dots_s = (float*)(smem + 20480);
  unsigned short* a_s = (unsigned short*)(smem + 32768);

  int tid = threadIdx.x;
  int b = blockIdx.y;
  int wv = tid >> 6, ln = tid & 63, q = ln >> 4, mr = ln & 15;
  int sw = (tid >> 3) & 3;

  bf16x8 Aq = *(const bf16x8*)(qkB + b * 512 + mr * 32 + q * 8);

  // constant ones B-fragment (bf16 1.0 splat) — replaces the per-chunk gather
  bf16x8 Bo;
#pragma unroll
  for (int e = 0; e < 8; e++) ((short*)&Bo)[e] = (short)0x3f80;

  f32x4 uacc0 = (f32x4){0.f, 0.f, 0.f, 0.f};
  f32x4 uacc1 = (f32x4){0.f, 0.f, 0.f, 0.f};
  f32x4 racc  = (f32x4){0.f, 0.f, 0.f, 0.f};

#pragma unroll 1
  for (int cc = 0; cc < 4; cc++) {
    int j0 = (blockIdx.x * 4 + cc) * 256;
    int j = j0 + tid;
    bool valid = j < D3S;

    // phase 0: global feat -> wave-private LDS rows (granule-swizzled)
    uint4 f4[4];
    if (valid) {
      const uint4* fp = (const uint4*)(feat + ((size_t)b * D3S + j) * C);
#pragma unroll
      for (int g = 0; g < 4; g++) f4[g] = fp[g];
    } else {
#pragma unroll
      for (int g = 0; g < 4; g++) f4[g] = (uint4){0u, 0u, 0u, 0u};
    }
#pragma unroll
    for (int g = 0; g < 4; g++) *(uint4*)(f_s + tid * 80 + ((g ^ sw) << 4)) = f4[g];
    asm volatile("s_waitcnt lgkmcnt(0)" ::: "memory");
    __builtin_amdgcn_sched_barrier(0);

    // phase 1: dots via MFMA (wave-private rows)
    f32x4 dacc[4];
#pragma unroll
    for (int mt = 0; mt < 4; mt++) {
      int jrow = wv * 64 + mt * 16 + mr;
      int sw1 = (jrow >> 3) & 3;
      bf16x8 Bf = *(const bf16x8*)(f_s + jrow * 80 + ((q ^ sw1) << 4));
      dacc[mt] = __builtin_amdgcn_mfma_f32_16x16x32_bf16(
          Aq, Bf, (f32x4){0.f, 0.f, 0.f, 0.f}, 0, 0, 0);
    }
    if (q < 2) {
#pragma unroll
      for (int mt = 0; mt < 4; mt++)
#pragma unroll
        for (int r = 0; r < 4; r++)
          dots_s[(wv * 64 + mt * 16 + mr) * 12 + q * 4 + r] = dacc[mt][r];
    }
    asm volatile("s_waitcnt lgkmcnt(0)" ::: "memory");
    __builtin_amdgcn_sched_barrier(0);

    // softmax over slots (thread = its j)
    float attn[NSLOT];
    {
      uint4 d0 = *(const uint4*)(dots_s + tid * 12);
      uint4 d1 = *(const uint4*)(dots_s + tid * 12 + 4);
      float dot[NSLOT] = {__uint_as_float(d0.x), __uint_as_float(d0.y),
                          __uint_as_float(d0.z), __uint_as_float(d0.w),
                          __uint_as_float(d1.x), __uint_as_float(d1.y),
                          __uint_as_float(d1.z), __uint_as_float(d1.w)};
      float mx = -1e30f;
#pragma unroll
      for (int i = 0; i < NSLOT; i++) { dot[i] *= 0.125f; mx = fmaxf(mx, dot[i]); }
      float ssum = 0.f;
#pragma unroll
      for (int i = 0; i < NSLOT; i++) { float e = __expf(dot[i] - mx); attn[i] = e; ssum += e; }
      float invs = 1.f / ssum;
#pragma unroll
      for (int i = 0; i < NSLOT; i++)
        attn[i] = valid ? fmaf(attn[i], invs, 1e-8f) : 0.f;
    }
#pragma unroll
    for (int i = 0; i < NSLOT; i++)
      a_s[i * 264 + tid] = f2bf(attn[i]);
    if (last && valid) {
#pragma unroll
      for (int i = 0; i < NSLOT; i++)
        attn_out[(size_t)(b * NSLOT + i) * D3S + j] = attn[i];
    }
    asm volatile("s_waitcnt lgkmcnt(0)" ::: "memory");
    __builtin_amdgcn_sched_barrier(0);

    // phase 2: per-wave K-split MFMA; accumulate across chunks
    {
      int kb0 = wv * 64;
#pragma unroll
      for (int ks = 0; ks < 2; ks++) {
        int kb = kb0 + ks * 32;
        bf16x8 Aa = *(const bf16x8*)(a_s + (mr & 7) * 264 + kb + q * 8);
        int jb = kb + q * 8;
        int sw2 = (jb >> 3) & 3;
        const char* colp = f_s + jb * 80;
        bf16x8 Bf0, Bf1;
        short* p0 = (short*)&Bf0;
        short* p1 = (short*)&Bf1;
#pragma unroll
        for (int e = 0; e < 8; e++) {
          const char* rowp = colp + e * 80;
          p0[e] = *(const short*)(rowp + ((((mr >> 3) ^ sw2) << 4)) + (mr & 7) * 2);
          p1[e] = *(const short*)(rowp + ((((2 + (mr >> 3)) ^ sw2) << 4)) + (mr & 7) * 2);
        }
        uacc0 = __builtin_amdgcn_mfma_f32_16x16x32_bf16(Aa, Bf0, uacc0, 0, 0, 0);
        uacc1 = __builtin_amdgcn_mfma_f32_16x16x32_bf16(Aa, Bf1, uacc1, 0, 0, 0);
        racc  = __builtin_amdgcn_mfma_f32_16x16x32_bf16(Aa, Bo,  racc,  0, 0, 0);
      }
    }
    // WAR fence: next chunk's f_s/a_s writes must not pass this chunk's reads
    asm volatile("s_waitcnt lgkmcnt(0)" ::: "memory");
    __builtin_amdgcn_sched_barrier(0);
  }

  // block-level combine (overlay on f_s; barrier covers all waves' last reads)
  float* part = (float*)smem;               // 4 waves x 264 floats
  __syncthreads();
  if (q < 2) {
    int base = wv * 264;
#pragma unroll
    for (int r = 0; r < 4; r++) {
      int i = q * 4 + r;
      part[base + i * 32 + mr] = uacc0[r];
      part[base + i * 32 + 16 + mr] = uacc1[r];
    }
    if (mr == 0) {
#pragma unroll
      for (int r = 0; r < 4; r++) part[base + 256 + q * 4 + r] = racc[r];
    }
  }
  __syncthreads();
  int gsl = blockIdx.x & (NRED - 1);
  if (tid < 256) {
    float s = part[tid] + part[264 + tid] + part[528 + tid] + part[792 + tid];
    atomicAdd(&red[gsl * REDS + b * 256 + tid], s);
  }
  if (tid < 8) {
    float s = part[256 + tid] + part[264 + 256 + tid] +
              part[528 + 256 + tid] + part[792 + 256 + tid];
    atomicAdd(&red[gsl * REDS + 512 + b * 8 + tid], s);
  }
}

// ---------------- final: 16 blocks (one per slot-row); NO red zeroing (triple-buffered) ----------------
__global__ __launch_bounds__(256) void k_final(const float* __restrict__ slots_src,
                                               const float* __restrict__ red,
                                               const float* __restrict__ vw,
                                               const float* __restrict__ wih,
                                               const float* __restrict__ whh,
                                               const float* __restrict__ bih,
                                               const float* __restrict__ bhh,
                                               const float* __restrict__ rlng,
                                               const float* __restrict__ rlnb,
                                               const float* __restrict__ w1,
                                               const float* __restrict__ rb1,
                                               const float* __restrict__ w2,
                                               const float* __restrict__ rb2,
                                               const float* __restrict__ qlng,
                                               const float* __restrict__ qlnb,
                                               const float* __restrict__ qw,
                                               const float* __restrict__ kw,
                                               unsigned short* __restrict__ qkB,
                                               float* __restrict__ slots_dst,
                                               float* __restrict__ out_slots,
                                               int last) {
  __shared__ float updc[32];
  __shared__ float rs_s;
  __shared__ float hh[64], upd_s[64], gg[384], hn[64], tl[64], m1[128], qv[64], ov_s[64];
  int tid = threadIdx.x;
  int r = blockIdx.x;            // 0..15
  int b = r >> 3, islot = r & 7;

  if (tid < 32) {
    float s = 0.f;
#pragma unroll
    for (int g = 0; g < NRED; g++) s += red[g * REDS + r * 32 + tid];
    updc[tid] = s;
  } else if (tid == 32) {
    float s = 0.f;
#pragma unroll
    for (int g = 0; g < NRED; g++) s += red[g * REDS + 512 + r];
    rs_s = s;
  }
  if (tid >= 64 && tid < 128) hh[tid - 64] = slots_src[r * 64 + (tid - 64)];
  __syncthreads();
  if (tid < 64) {
    float s = 0.f;
    for (int c = 0; c < 32; c++) s = fmaf(updc[c], vw[tid * 32 + c], s);
    upd_s[tid] = s / rs_s;
  }
  __syncthreads();
  for (int o = tid; o < 384; o += 256) {
    int sel = o >= 192;
    int cg = o - sel * 192;
    const float* sp = sel ? hh : upd_s;
    const float* w  = sel ? whh : wih;
    float s = sel ? bhh[cg] : bih[cg];
    for (int d = 0; d < 64; d++) s = fmaf(sp[d], w[cg * 64 + d], s);
    gg[o] = s;
  }
  __syncthreads();
  if (tid < 64) {
    float rg = 1.f / (1.f + __expf(-(gg[tid] + gg[192 + tid])));
    float zg = 1.f / (1.f + __expf(-(gg[64 + tid] + gg[256 + tid])));
    float ng = tanhf(gg[128 + tid] + rg * gg[320 + tid]);
    hn[tid] = (1.f - zg) * ng + zg * hh[tid];
  }
  __syncthreads();
  if (tid < 64) {
    float v = hn[tid];
    float s = v, s2 = v * v;
#pragma unroll
    for (int m = 1; m < 64; m <<= 1) { s += __shfl_xor(s, m); s2 += __shfl_xor(s2, m); }
    float mean = s * (1.f / 64);
    float inv = rsqrtf(s2 * (1.f / 64) - mean * mean + 1e-5f);
    tl[tid] = (v - mean) * inv * rlng[tid] + rlnb[tid];
  }
  __syncthreads();
  if (tid < 128) {
    float s = rb1[tid];
    for (int d = 0; d < 64; d++) s = fmaf(tl[d], w1[tid * 64 + d], s);
    m1[tid] = fmaxf(s, 0.f);
  }
  __syncthreads();
  if (tid < 64) {
    float s = rb2[tid];
    for (int j = 0; j < 128; j++) s = fmaf(m1[j], w2[tid * 128 + j], s);
    float ov = hn[tid] + s;
    slots_dst[r * 64 + tid] = ov;
    ov_s[tid] = ov;
    if (last) out_slots[r * 64 + tid] = ov;
  }
  __syncthreads();
  if (tid < 64) {
    float v = ov_s[tid];
    float s = v, s2 = v * v;
#pragma unroll
    for (int m = 1; m < 64; m <<= 1) { s += __shfl_xor(s, m); s2 += __shfl_xor(s2, m); }
    float mean = s * (1.f / 64);
    float inv = rsqrtf(s2 * (1.f / 64) - mean * mean + 1e-5f);
    tl[tid] = (v - mean) * inv * qlng[tid] + qlnb[tid];
  }
  __syncthreads();
  if (tid < 64) {
    float s = 0.f;
    for (int c = 0; c < 64; c++) s = fmaf(tl[c], qw[tid * 64 + c], s);
    qv[tid] = s;
  }
  __syncthreads();
  if (tid < 32) {
    float s = 0.f;
    for (int d = 0; d < 64; d++) s = fmaf(qv[d], kw[d * 32 + tid], s);
    qkB[b * 512 + islot * 32 + tid] = f2bf(s);
  }
}

// ---------------- host launch ----------------
extern "C" void kernel_launch(void* const* d_in, const int* in_sizes, int n_in,
                              void* d_out, int out_size, void* d_ws, size_t ws_size,
                              hipStream_t stream) {
  const float* slots = (const float*)d_in[0];
  const float* oin   = (const float*)d_in[1];
  const float* w1    = (const float*)d_in[2];
  const float* b1    = (const float*)d_in[3];
  const float* w2    = (const float*)d_in[4];
  const float* b2    = (const float*)d_in[5];
  const float* w3    = (const float*)d_in[6];
  const float* b3    = (const float*)d_in[7];
  const float* kw    = (const float*)d_in[8];
  const float* vw    = (const float*)d_in[9];
  const float* qlng  = (const float*)d_in[10];
  const float* qlnb  = (const float*)d_in[11];
  const float* qw    = (const float*)d_in[12];
  const float* wih   = (const float*)d_in[13];
  const float* whh   = (const float*)d_in[14];
  const float* bih   = (const float*)d_in[15];
  const float* bhh   = (const float*)d_in[16];
  const float* rlng  = (const float*)d_in[17];
  const float* rlnb  = (const float*)d_in[18];
  const float* rw1   = (const float*)d_in[19];
  const float* rb1   = (const float*)d_in[20];
  const float* rw2   = (const float*)d_in[21];
  const float* rb2   = (const float*)d_in[22];
  const float* flng  = (const float*)d_in[23];
  const float* flnb  = (const float*)d_in[24];

  char* ws = (char*)d_ws;
  unsigned short* act1 = (unsigned short*)ws;
  unsigned short* act2 = (unsigned short*)(ws + A1_BYTES);
  unsigned short* feat = act1;
  unsigned short* wB1 = (unsigned short*)(ws + S_OFF);
  unsigned short* wB2 = wB1 + 4096;
  unsigned short* wB3 = wB2 + 27648;
  unsigned short* qkB = wB3 + 27648;           // [2][16][32] bf16
  float* red  = (float*)(qkB + 1024);          // 3 * NRED*REDS floats
  float* sl0  = red + 3 * NRED * REDS;
  float* sl1  = sl0 + 1024;

  float* out_slots = (float*)d_out;
  float* attn_out  = (float*)d_out + 1024;

  k_wtr<<<233, 256, 0, stream>>>(w1, w2, w3, wB1, wB2, wB3, red,
                                 slots, qlng, qlnb, qw, kw, qkB);
  k_conv1m<<<C1NX * C1NY * C1NZ * BATCH, 512, 0, stream>>>(oin, wB1, b1, act1);
  {
    constexpr int NB2 = ((D2 + 15) / 16) * ((D2 + 3) / 4) * ((D2 + 7) / 8) * BATCH;
    k_convm<D1, D2, false><<<NB2, 512, 0, stream>>>(act1, wB2, b2, nullptr, nullptr, act2);
  }
  {
    constexpr int NB3 = ((D3 + 15) / 16) * ((D3 + 3) / 4) * ((D3 + 7) / 8) * BATCH;
    k_convm<D2, D3, true><<<NB3, 512, 0, stream>>>(act2, wB3, b3, flng, flnb, feat);
  }

  const float* src = slots;
  float* dst = sl0;
  for (int it = 0; it < 3; it++) {
    int last = (it == 2);
    float* red_it = red + it * (NRED * REDS);
    k_attn<<<dim3(NCHUNK4, BATCH), 256, 0, stream>>>(feat, qkB, red_it, attn_out, last);
    k_final<<<16, 256, 0, stream>>>(src, red_it, vw, wih, whh, bih, bhh,
                                    rlng, rlnb, rw1, rb1, rw2, rb2,
                                    qlng, qlnb, qw, kw, qkB, dst, out_slots, last);
    src = dst;
    dst = (it == 0) ? sl1 : sl0;
  }
}